// Round 2
// baseline (95.289 us; speedup 1.0000x reference)
//
#include <hip/hip_runtime.h>
#include <math.h>

// Problem constants (from reference): B=2048, P_ROWS=128, N=64, Q=8
#define NB    2048
#define PROWS 128
#define NDIM  64
#define QCNT  8

// One block per batch element. 256 threads = 4 waves.
// Memory-bound: streams A1 (32KB/batch) + P (128KB/batch) exactly once.
// Key structure: ALL global loads (40 float4/thread) issue with no
// intermediate syncs/reductions; single reduction epilogue.
// Norm trick: out = z0 + min(1/kraw,1)*v where kraw uses raw v
// (all kappa terms scale as 1/||v||, which cancels against alpha).
__global__ __launch_bounds__(256) void constraint_kernel(
    const float* __restrict__ v,    // (B, 64)
    const float* __restrict__ A1,   // (B, 128, 64)
    const float* __restrict__ b1,   // (B, 128)
    const float* __restrict__ z0,   // (B, 64)
    const float* __restrict__ P,    // (B, 8, 64, 64)
    const float* __restrict__ qv,   // (B, 8, 64)
    const float* __restrict__ rr,   // (B, 8)
    float* __restrict__ out)        // (B, 64)
{
    const int b   = blockIdx.x;
    const int tid = threadIdx.x;

    __shared__ __align__(16) float s_v[NDIM];
    __shared__ __align__(16) float s_z[NDIM];
    __shared__ float s_red[4][QCNT][4];  // per-wave, per-q partial sums
    __shared__ float s_lin[4];           // per-wave linear max
    __shared__ float s_beta;

    // ---------- Stage v, z0 (one sync; no norm needed) ----------
    if (tid < NDIM) {
        s_v[tid] = v[b * NDIM + tid];
        s_z[tid] = z0[b * NDIM + tid];
    }
    __syncthreads();

    // ================= LOAD + ACCUMULATE (no syncs, no shuffles) ==========
    // ---- Phase B: A1 rows. thread = (grp = tid>>4 in [0,16), sub = tid&15)
    // handles rows {p*16+grp}, cols sub*4..sub*4+3. 8 float4 loads.
    const int sub = tid & 15;
    const int grp = tid >> 4;
    const float4 vB = *(const float4*)&s_v[sub * 4];
    const float4 zB = *(const float4*)&s_z[sub * 4];
    float dv[8], dz[8];
    const float* A1b = A1 + (size_t)b * PROWS * NDIM;
    #pragma unroll
    for (int p = 0; p < 8; ++p) {
        const float4 a = *(const float4*)&A1b[(p * 16 + grp) * NDIM + sub * 4];
        dv[p] = a.x * vB.x + a.y * vB.y + a.z * vB.z + a.w * vB.w;
        dz[p] = a.x * zB.x + a.y * zB.y + a.z * zB.z + a.w * zB.w;
    }

    // ---- Phase C: P bilinear partials. thread = (i = tid>>2, s4 = tid&3)
    // owns row i, cols {k*16+s4*4..+3, k=0..3}. 32 float4 loads.
    const int i  = tid >> 2;
    const int s4 = tid & 3;
    float4 vj[4], zj[4];
    #pragma unroll
    for (int k = 0; k < 4; ++k) {
        vj[k] = *(const float4*)&s_v[k * 16 + s4 * 4];
        zj[k] = *(const float4*)&s_z[k * 16 + s4 * 4];
    }
    float drq[QCNT], dyq[QCNT];
    const float* Pb = P + (size_t)b * QCNT * NDIM * NDIM + i * NDIM;
    #pragma unroll
    for (int qq = 0; qq < QCNT; ++qq) {
        const float* Pq = Pb + qq * NDIM * NDIM;
        float dr = 0.f, dy = 0.f;
        #pragma unroll
        for (int k = 0; k < 4; ++k) {
            const float4 p4 = *(const float4*)&Pq[k * 16 + s4 * 4];
            dr += p4.x * vj[k].x + p4.y * vj[k].y + p4.z * vj[k].z + p4.w * vj[k].w;
            dy += p4.x * zj[k].x + p4.y * zj[k].y + p4.z * zj[k].z + p4.w * zj[k].w;
        }
        drq[qq] = dr;
        dyq[qq] = dy;
    }

    // ================= REDUCTION EPILOGUE =================
    // ---- Phase B reduce: sum over 16-lane column groups (xor 8,4,2,1)
    float lmax = -INFINITY;
    #pragma unroll
    for (int p = 0; p < 8; ++p) {
        float a = dv[p], c = dz[p];
        #pragma unroll
        for (int m = 8; m >= 1; m >>= 1) {
            a += __shfl_xor(a, m);
            c += __shfl_xor(c, m);
        }
        if (sub == 0) {
            const float denom = b1[b * PROWS + p * 16 + grp] - c;  // > 0
            lmax = fmaxf(lmax, a / denom);
        }
    }
    #pragma unroll
    for (int m = 32; m >= 1; m >>= 1) lmax = fmaxf(lmax, __shfl_xor(lmax, m));
    if ((tid & 63) == 0) s_lin[tid >> 6] = lmax;

    // ---- Phase C reduce: per-q wave reduction of 4 bilinear partials
    const float vi = s_v[i];
    const float zi = s_z[i];
    #pragma unroll
    for (int qq = 0; qq < QCNT; ++qq) {
        float a0 = vi * drq[qq];   // -> v^T P v
        float a1 = vi * dyq[qq];   // -> v^T P z0 (part of g.v)
        float a2 = zi * dyq[qq];   // -> z0^T P z0
        float a3 = 0.f;            // -> q.z0
        if (s4 == 0) {
            const float qvi = qv[(size_t)b * QCNT * NDIM + qq * NDIM + i];
            a1 += qvi * vi;        // + q.v completes g.v
            a3  = qvi * zi;
        }
        #pragma unroll
        for (int m = 32; m >= 1; m >>= 1) {
            a0 += __shfl_xor(a0, m);
            a1 += __shfl_xor(a1, m);
            a2 += __shfl_xor(a2, m);
            a3 += __shfl_xor(a3, m);
        }
        if ((tid & 63) == 0) {
            const int w = tid >> 6;
            s_red[w][qq][0] = a0; s_red[w][qq][1] = a1;
            s_red[w][qq][2] = a2; s_red[w][qq][3] = a3;
        }
    }
    __syncthreads();

    // ---- Final: threads 0..7 each handle one q; combine; write beta
    float kq = -INFINITY;
    if (tid < QCNT) {
        const float vPv = s_red[0][tid][0] + s_red[1][tid][0] + s_red[2][tid][0] + s_red[3][tid][0];
        const float grw = s_red[0][tid][1] + s_red[1][tid][1] + s_red[2][tid][1] + s_red[3][tid][1];
        const float yPy = s_red[0][tid][2] + s_red[1][tid][2] + s_red[2][tid][2] + s_red[3][tid][2];
        const float qy  = s_red[0][tid][3] + s_red[1][tid][3] + s_red[2][tid][3] + s_red[3][tid][3];
        const float c0    = 0.5f * yPy + qy + rr[b * QCNT + tid];
        const float sigma = 2.f * c0;
        const float quad  = (grw * grw - 2.f * c0 * vPv) / (sigma * sigma);
        kq = -grw / sigma + sqrtf(quad);
    }
    #pragma unroll
    for (int m = 4; m >= 1; m >>= 1) kq = fmaxf(kq, __shfl_xor(kq, m));
    if (tid == 0) {
        const float klin = fmaxf(fmaxf(s_lin[0], s_lin[1]), fmaxf(s_lin[2], s_lin[3]));
        const float kraw = fmaxf(fmaxf(klin, 0.f), kq);
        s_beta = fminf(1.f / kraw, 1.f);  // 1/0 = inf -> 1 (alpha = ||v||)
    }
    __syncthreads();
    if (tid < NDIM) {
        out[b * NDIM + tid] = s_z[tid] + s_beta * s_v[tid];
    }
}

extern "C" void kernel_launch(void* const* d_in, const int* in_sizes, int n_in,
                              void* d_out, int out_size, void* d_ws, size_t ws_size,
                              hipStream_t stream) {
    const float* v  = (const float*)d_in[0];
    const float* A1 = (const float*)d_in[1];
    const float* b1 = (const float*)d_in[2];
    const float* z0 = (const float*)d_in[3];
    const float* P  = (const float*)d_in[4];
    const float* qv = (const float*)d_in[5];
    const float* rr = (const float*)d_in[6];
    float* out = (float*)d_out;

    constraint_kernel<<<NB, 256, 0, stream>>>(v, A1, b1, z0, P, qv, rr, out);
}